// Round 1
// 618.711 us; speedup vs baseline: 1.0635x; 1.0635x over previous
//
#include <hip/hip_runtime.h>
#include <stdint.h>
#include <stddef.h>

// ---------- types ----------
typedef __bf16 bf16_t;
typedef __attribute__((ext_vector_type(8))) __bf16 bf16x8;
typedef __attribute__((ext_vector_type(4))) float f32x4;

#define LT 1024
#define LS 1024
#define DM 1024
#define NH 16
#define HD 64
#define FF 4096
#define BB 4

// async global->LDS, 16B per lane; LDS deposit = wave-uniform base + lane*16
__device__ __forceinline__ void gld_lds16(const bf16_t* g, bf16_t* l) {
    __builtin_amdgcn_global_load_lds(
        (const __attribute__((address_space(1))) void*)g,
        (__attribute__((address_space(3))) void*)l, 16, 0, 0);
}

// ---------- weight transpose fp32[R,C] -> bf16[C,R] ----------
__global__ __launch_bounds__(256) void transpose_f2bf(
    const float* __restrict__ in, bf16_t* __restrict__ out, int R, int C)
{
    __shared__ float tile[32][33];
    int bx = blockIdx.x * 32;
    int by = blockIdx.y * 32;
    int tx = threadIdx.x, ty = threadIdx.y;   // (32, 8)
#pragma unroll
    for (int j = 0; j < 4; j++)
        tile[ty + j * 8][tx] = in[(size_t)(by + ty + j * 8) * C + bx + tx];
    __syncthreads();
#pragma unroll
    for (int j = 0; j < 4; j++)
        out[(size_t)(bx + ty + j * 8) * R + by + tx] = (bf16_t)tile[tx][ty + j * 8];
}

// ---------- fused 8x 1024x1024 weight transposes (one launch) ----------
struct TPtrs { const float* in[8]; bf16_t* out[8]; };
__global__ __launch_bounds__(256) void transpose8_f2bf(TPtrs p)
{
    __shared__ float tile[32][33];
    const float* in = p.in[blockIdx.z];
    bf16_t* out = p.out[blockIdx.z];
    int bx = blockIdx.x * 32;
    int by = blockIdx.y * 32;
    int tx = threadIdx.x, ty = threadIdx.y;   // (32, 8)
#pragma unroll
    for (int j = 0; j < 4; j++)
        tile[ty + j * 8][tx] = in[(size_t)(by + ty + j * 8) * 1024 + bx + tx];
    __syncthreads();
#pragma unroll
    for (int j = 0; j < 4; j++)
        out[(size_t)(bx + ty + j * 8) * 1024 + by + tx] = (bf16_t)tile[tx][ty + j * 8];
}

// ---------- bf16 per-(b,h) transpose: [BH,L,HD] -> [BH,HD,L] ----------
__global__ __launch_bounds__(256) void transpose_bf(
    const bf16_t* __restrict__ in, bf16_t* __restrict__ out)
{
    __shared__ bf16_t tile[32][33];
    int bh = blockIdx.z;
    int r0 = blockIdx.x * 32;   // L dim
    int c0 = blockIdx.y * 32;   // HD dim
    const bf16_t* ib = in + (size_t)bh * LT * HD;
    bf16_t* ob = out + (size_t)bh * HD * LT;
    int tx = threadIdx.x, ty = threadIdx.y;
#pragma unroll
    for (int j = 0; j < 4; j++)
        tile[ty + j * 8][tx] = ib[(size_t)(r0 + ty + j * 8) * HD + c0 + tx];
    __syncthreads();
#pragma unroll
    for (int j = 0; j < 4; j++)
        ob[(size_t)(c0 + ty + j * 8) * LT + r0 + tx] = tile[tx][ty + j * 8];
}

// ---------- fp32 -> bf16 convert ----------
__global__ __launch_bounds__(256) void f2bf_kernel(
    const float* __restrict__ in, bf16_t* __restrict__ out, size_t n)
{
    size_t i = ((size_t)blockIdx.x * 256 + threadIdx.x) * 4;
    if (i + 3 < n) {
        float4 v = *(const float4*)&in[i];
        out[i + 0] = (bf16_t)v.x;
        out[i + 1] = (bf16_t)v.y;
        out[i + 2] = (bf16_t)v.z;
        out[i + 3] = (bf16_t)v.w;
    }
}

// ---------- split-K reduce + residual: out = p[0] + p[1] + res ----------
__global__ __launch_bounds__(256) void reduce2_res(
    const float* __restrict__ p, const float* __restrict__ res,
    float* __restrict__ out)
{
    const size_t MN = (size_t)BB * LT * DM;
    size_t i = ((size_t)blockIdx.x * 256 + threadIdx.x) * 4;
    float4 a = *(const float4*)&p[i];
    float4 b = *(const float4*)&p[i + MN];
    float4 r = *(const float4*)&res[i];
    float4 o;
    o.x = a.x + b.x + r.x; o.y = a.y + b.y + r.y;
    o.z = a.z + b.z + r.z; o.w = a.w + b.w + r.w;
    *(float4*)&out[i] = o;
}

// ---------- RMSNorm: fp32 row -> bf16 row ----------
__global__ __launch_bounds__(256) void rmsnorm_kernel(
    const float* __restrict__ x, const float* __restrict__ g,
    bf16_t* __restrict__ out)
{
    __shared__ float red[4];
    int row = blockIdx.x;
    int t = threadIdx.x;
    int lane = t & 63, w = t >> 6;
    const float* xr = x + (size_t)row * DM;
    float4 v = *(const float4*)&xr[t * 4];
    float ss = v.x * v.x + v.y * v.y + v.z * v.z + v.w * v.w;
#pragma unroll
    for (int off = 32; off > 0; off >>= 1) ss += __shfl_down(ss, off, 64);
    if (lane == 0) red[w] = ss;
    __syncthreads();
    float tot = red[0] + red[1] + red[2] + red[3];
    float inv = rsqrtf(tot * (1.0f / DM) + 1e-6f);
    float4 gv = *(const float4*)&g[t * 4];
    bf16_t* o = out + (size_t)row * DM + t * 4;
    o[0] = (bf16_t)(v.x * inv * gv.x);
    o[1] = (bf16_t)(v.y * inv * gv.y);
    o[2] = (bf16_t)(v.z * inv * gv.z);
    o[3] = (bf16_t)(v.w * inv * gv.w);
}

// ================= GEMM core (shared tile loop) =================
// acc += A[m0:m0+128, kBeg:kEnd] * Bt[n0:n0+128, kBeg:kEnd]^T
#define GEMM_BODY(Aptr, Btptr, Kstride, kBeg, kEnd)                              \
    for (int k0 = (kBeg); k0 < (kEnd); k0 += 64) {                               \
        __syncthreads();                                                         \
        _Pragma("unroll")                                                        \
        for (int i = 0; i < 4; i++) {                                            \
            int p = i * 256 + t;                                                 \
            int row = p >> 3;                                                    \
            int g = (p & 7) ^ (row & 7);                                         \
            gld_lds16(&(Aptr)[(size_t)(m0 + row) * (Kstride) + k0 + g * 8],      \
                      &lA[p * 8]);                                               \
            gld_lds16(&(Btptr)[(size_t)(n0 + row) * (Kstride) + k0 + g * 8],     \
                      &lB[p * 8]);                                               \
        }                                                                        \
        __syncthreads();                                                         \
        _Pragma("unroll")                                                        \
        for (int s = 0; s < 2; s++) {                                            \
            bf16x8 af[4], bfr[4];                                                \
            _Pragma("unroll")                                                    \
            for (int mt = 0; mt < 4; mt++) {                                     \
                int r = wr * 64 + mt * 16 + l15;                                 \
                af[mt] = *(const bf16x8*)&lA[((r << 3) + ((s * 4 + quad) ^ (r & 7))) << 3]; \
            }                                                                    \
            _Pragma("unroll")                                                    \
            for (int nt = 0; nt < 4; nt++) {                                     \
                int r = wc * 64 + nt * 16 + l15;                                 \
                bfr[nt] = *(const bf16x8*)&lB[((r << 3) + ((s * 4 + quad) ^ (r & 7))) << 3]; \
            }                                                                    \
            _Pragma("unroll")                                                    \
            for (int mt = 0; mt < 4; mt++)                                       \
                _Pragma("unroll")                                                \
                for (int nt = 0; nt < 4; nt++)                                   \
                    acc[mt][nt] = __builtin_amdgcn_mfma_f32_16x16x32_bf16(       \
                        af[mt], bfr[nt], acc[mt][nt], 0, 0, 0);                  \
        }                                                                        \
    }

// ---------- QKV projection GEMM (dual-source, head-layout epilogue) ----------
// grid.y < nb1 : A1*B1 (sections from secbase1); else A2*B2 (secbase2)
__global__ __launch_bounds__(256) void gemm_qkv(
    const bf16_t* __restrict__ A1, const bf16_t* __restrict__ B1, int nb1,
    const bf16_t* __restrict__ A2, const bf16_t* __restrict__ B2, int secbase2,
    bf16_t* __restrict__ qb,
    float* __restrict__ kF, bf16_t* __restrict__ kB,
    float* __restrict__ vF, bf16_t* __restrict__ vB)
{
    __shared__ bf16_t lA[128 * 64];
    __shared__ bf16_t lB[128 * 64];
    const int t = threadIdx.x;
    const int lane = t & 63, w = t >> 6;
    const int quad = lane >> 4, l15 = lane & 15;
    const int m0 = blockIdx.x * 128;
    const int wr = w >> 1, wc = w & 1;

    const bf16_t* A; const bf16_t* Bt; int n0, sec0;
    if ((int)blockIdx.y < nb1) { A = A1; Bt = B1; n0 = blockIdx.y * 128; sec0 = 0; }
    else { A = A2; Bt = B2; n0 = (blockIdx.y - nb1) * 128; sec0 = secbase2; }

    f32x4 acc[4][4] = {};
    GEMM_BODY(A, Bt, 1024, 0, 1024)

#pragma unroll
    for (int mt = 0; mt < 4; mt++) {
#pragma unroll
        for (int nt = 0; nt < 4; nt++) {
#pragma unroll
            for (int r = 0; r < 4; r++) {
                int row = m0 + wr * 64 + mt * 16 + quad * 4 + r;
                int col = n0 + wc * 64 + nt * 16 + l15;
                float v = acc[mt][nt][r];
                int b = row >> 10, tp = row & 1023;
                int sec = sec0 + (col >> 10);
                int c10 = col & 1023;
                int h = c10 >> 6, d = c10 & 63;
                size_t idx = (((size_t)(b * NH + h)) << 16) + (size_t)tp * HD + d;
                if (sec == 0) {
                    qb[idx] = (bf16_t)v;
                } else if (sec == 1) {
                    kF[idx] = v;
                    kB[idx] = (bf16_t)v;
                } else {
                    vF[idx] = v;
                    vB[idx] = (bf16_t)v;
                }
            }
        }
    }
}

// ---------- general GEMM: C[M,N] = A[M,K] * Bt[N,K]^T ----------
#define EP_RES 0    // fp32 store of (v + res)
#define EP_RELU 1   // bf16 relu store
#define EP_PART 2   // fp32 store to partial slice (split-K)

template <int EP, int KSPLIT>
__global__ __launch_bounds__(256) void gemm_bt(
    const bf16_t* __restrict__ A, const bf16_t* __restrict__ Bt,
    int N, int K,
    float* __restrict__ outF, const float* __restrict__ res,
    bf16_t* __restrict__ outB)
{
    __shared__ bf16_t lA[128 * 64];
    __shared__ bf16_t lB[128 * 64];
    const int t = threadIdx.x;
    const int lane = t & 63, w = t >> 6;
    const int quad = lane >> 4, l15 = lane & 15;
    const int m0 = blockIdx.x * 128, n0 = blockIdx.y * 128;
    const int wr = w >> 1, wc = w & 1;
    const int Kc = K / KSPLIT;
    const int kBeg = blockIdx.z * Kc;

    f32x4 acc[4][4] = {};
    GEMM_BODY(A, Bt, K, kBeg, kBeg + Kc)

    float* dst = outF;
    if constexpr (EP == EP_PART)
        dst = outF + (size_t)blockIdx.z * (size_t)gridDim.x * 128 * N;

#pragma unroll
    for (int mt = 0; mt < 4; mt++) {
#pragma unroll
        for (int nt = 0; nt < 4; nt++) {
#pragma unroll
            for (int r = 0; r < 4; r++) {
                int row = m0 + wr * 64 + mt * 16 + quad * 4 + r;
                int col = n0 + wc * 64 + nt * 16 + l15;
                float v = acc[mt][nt][r];
                if constexpr (EP == EP_RES) {
                    dst[(size_t)row * N + col] = v + res[(size_t)row * N + col];
                } else if constexpr (EP == EP_RELU) {
                    outB[(size_t)row * N + col] = (bf16_t)fmaxf(v, 0.0f);
                } else {
                    dst[(size_t)row * N + col] = v;
                }
            }
        }
    }
}

// ---------- flash attention ----------
// Double-buffered K/V via gld_lds + raw s_barrier + counted vmcnt (prefetch
// stays in flight across the barrier); bias prefetched to regs one tile ahead.
// Grid y is batch-minor (h = y>>2, b = y&3) so the 4 batch-duplicates of a
// bias slice are consecutive ids 16 apart -> same XCD (id%8) -> L2 reuse.
template <bool CAUSAL>
__global__ __launch_bounds__(256, 4) void flash_attn(
    const bf16_t* __restrict__ Q, const bf16_t* __restrict__ Kb,
    const bf16_t* __restrict__ Vt, const float* __restrict__ bias,
    bf16_t* __restrict__ O)
{
    __shared__ bf16_t lK[2][64 * 64];
    __shared__ bf16_t lV[2][64 * 64];
    __shared__ bf16_t lP[4][16 * 64];
    const int t = threadIdx.x;
    const int lane = t & 63, w = t >> 6;
    const int quad = lane >> 4, l15 = lane & 15;
    const int qt = blockIdx.x;
    const int yy = blockIdx.y;
    const int h = yy >> 2, b = yy & 3;       // batch-minor decode
    const int bhd = b * NH + h;              // data index (layout is [B,H,...])
    const int q0 = qt * 64;

    const bf16_t* qbase = Q + (size_t)bhd * LT * HD;
    const bf16_t* kbase = Kb + (size_t)bhd * LS * HD;
    const bf16_t* vbase = Vt + (size_t)bhd * HD * LS;
    const float* bbase = bias + (size_t)h * LT * LS;   // unused when CAUSAL

    bf16x8 qf[2];
    int qrow = q0 + w * 16 + l15;
#pragma unroll
    for (int s = 0; s < 2; s++)
        qf[s] = *(const bf16x8*)&qbase[(size_t)qrow * HD + s * 32 + quad * 8];

    f32x4 acc_o[4] = {};
    float m_i[4], l_i[4];
#pragma unroll
    for (int r = 0; r < 4; r++) { m_i[r] = -3.0e38f; l_i[r] = 0.0f; }

    const int nkt = CAUSAL ? (qt + 1) : (LS / 64);

    // ---- prologue: stage tile 0 into buf 0, prefetch bias tile 0 ----
#pragma unroll
    for (int i = 0; i < 2; i++) {
        int p = i * 256 + t;
        int row = p >> 3;
        int g = (p & 7) ^ (row & 7);
        gld_lds16(&kbase[(size_t)row * HD + g * 8], &lK[0][p * 8]);
        gld_lds16(&vbase[(size_t)row * LS + g * 8], &lV[0][p * 8]);
    }
    float bnxt[16], bcur[16];
    if constexpr (!CAUSAL) {
#pragma unroll
        for (int nt = 0; nt < 4; nt++)
#pragma unroll
            for (int r = 0; r < 4; r++)
                bnxt[nt * 4 + r] =
                    bbase[(size_t)(q0 + w * 16 + quad * 4 + r) * LS + nt * 16 + l15];
    }

    for (int kt = 0; kt < nkt; kt++) {
        const int d = kt & 1;
        const int nxt = kt + 1;
        if constexpr (!CAUSAL) {
#pragma unroll
            for (int i = 0; i < 16; i++) bcur[i] = bnxt[i];
        }
        if (nxt < nkt) {
            const int nb = nxt * 64;
            const int nd = nxt & 1;
#pragma unroll
            for (int i = 0; i < 2; i++) {
                int p = i * 256 + t;
                int row = p >> 3;
                int g = (p & 7) ^ (row & 7);
                gld_lds16(&kbase[(size_t)(nb + row) * HD + g * 8], &lK[nd][p * 8]);
                gld_lds16(&vbase[(size_t)row * LS + nb + g * 8], &lV[nd][p * 8]);
            }
            if constexpr (!CAUSAL) {
#pragma unroll
                for (int nt = 0; nt < 4; nt++)
#pragma unroll
                    for (int r = 0; r < 4; r++)
                        bnxt[nt * 4 + r] =
                            bbase[(size_t)(q0 + w * 16 + quad * 4 + r) * LS + nb + nt * 16 + l15];
                // 20 newest (4 gld_lds + 16 bias loads for nxt) may stay in
                // flight; everything older (tile kt) must have landed.
                asm volatile("s_waitcnt vmcnt(20)" ::: "memory");
            } else {
                asm volatile("s_waitcnt vmcnt(4)" ::: "memory");
            }
        } else {
            asm volatile("s_waitcnt vmcnt(0)" ::: "memory");
        }
        __builtin_amdgcn_s_barrier();
        __builtin_amdgcn_sched_barrier(0);   // keep LDS reads behind the rendezvous

        const int kb = kt * 64;
        f32x4 sacc[4];
#pragma unroll
        for (int nt = 0; nt < 4; nt++) {
            f32x4 sa = {};
#pragma unroll
            for (int s = 0; s < 2; s++) {
                int r = nt * 16 + l15;
                bf16x8 kf = *(const bf16x8*)&lK[d][((r << 3) + ((s * 4 + quad) ^ (r & 7))) << 3];
                sa = __builtin_amdgcn_mfma_f32_16x16x32_bf16(qf[s], kf, sa, 0, 0, 0);
            }
            sacc[nt] = sa;
        }

        float sval[4][4];
        float tmax[4];
#pragma unroll
        for (int r = 0; r < 4; r++) tmax[r] = -3.0e38f;
#pragma unroll
        for (int nt = 0; nt < 4; nt++) {
            int col = kb + nt * 16 + l15;
#pragma unroll
            for (int r = 0; r < 4; r++) {
                int row = q0 + w * 16 + quad * 4 + r;
                float v = sacc[nt][r] * 0.125f;
                if constexpr (CAUSAL) {
                    if (col > row) v = -1e9f;
                } else {
                    v += bcur[nt * 4 + r];
                }
                sval[nt][r] = v;
                tmax[r] = fmaxf(tmax[r], v);
            }
        }
#pragma unroll
        for (int r = 0; r < 4; r++) {
            float v = tmax[r];
            v = fmaxf(v, __shfl_xor(v, 1, 64));
            v = fmaxf(v, __shfl_xor(v, 2, 64));
            v = fmaxf(v, __shfl_xor(v, 4, 64));
            v = fmaxf(v, __shfl_xor(v, 8, 64));
            tmax[r] = v;
        }
        float alpha[4], rsum[4];
#pragma unroll
        for (int r = 0; r < 4; r++) {
            float mn = fmaxf(m_i[r], tmax[r]);
            alpha[r] = __expf(m_i[r] - mn);
            m_i[r] = mn;
            rsum[r] = 0.0f;
        }
#pragma unroll
        for (int nt = 0; nt < 4; nt++) {
#pragma unroll
            for (int r = 0; r < 4; r++) {
                float p = __expf(sval[nt][r] - m_i[r]);
                rsum[r] += p;
                int pr = quad * 4 + r;
                int gcol = nt * 2 + (l15 >> 3);
                lP[w][((pr << 3) + (gcol ^ (pr & 7))) * 8 + (l15 & 7)] = (bf16_t)p;
            }
        }
#pragma unroll
        for (int r = 0; r < 4; r++) {
            float v = rsum[r];
            v += __shfl_xor(v, 1, 64);
            v += __shfl_xor(v, 2, 64);
            v += __shfl_xor(v, 4, 64);
            v += __shfl_xor(v, 8, 64);
            l_i[r] = l_i[r] * alpha[r] + v;
        }
#pragma unroll
        for (int dt = 0; dt < 4; dt++)
#pragma unroll
            for (int r = 0; r < 4; r++)
                acc_o[dt][r] *= alpha[r];

#pragma unroll
        for (int s = 0; s < 2; s++) {
            bf16x8 pf = *(const bf16x8*)&lP[w][((l15 << 3) + ((s * 4 + quad) ^ (l15 & 7))) << 3];
#pragma unroll
            for (int dt = 0; dt < 4; dt++) {
                int r = dt * 16 + l15;
                bf16x8 vf = *(const bf16x8*)&lV[d][((r << 3) + ((s * 4 + quad) ^ (r & 7))) << 3];
                acc_o[dt] = __builtin_amdgcn_mfma_f32_16x16x32_bf16(pf, vf, acc_o[dt], 0, 0, 0);
            }
        }
        __builtin_amdgcn_s_barrier();   // all reads of buf[d] done before it is restaged
    }

#pragma unroll
    for (int dt = 0; dt < 4; dt++) {
#pragma unroll
        for (int r = 0; r < 4; r++) {
            int row = q0 + w * 16 + quad * 4 + r;
            int col = h * HD + dt * 16 + l15;
            float v = acc_o[dt][r] / l_i[r];
            O[((size_t)(b * LT + row)) * DM + col] = (bf16_t)v;
        }
    }
}

// ---------- host ----------
extern "C" void kernel_launch(void* const* d_in, const int* in_sizes, int n_in,
                              void* d_out, int out_size, void* d_ws, size_t ws_size,
                              hipStream_t stream)
{
    (void)in_sizes; (void)n_in; (void)out_size; (void)ws_size;
    const float* x    = (const float*)d_in[0];
    const float* mem  = (const float*)d_in[1];
    const float* pemb = (const float*)d_in[2];
    const float* g_sa = (const float*)d_in[4];
    const float* wq_s = (const float*)d_in[5];
    const float* wk_s = (const float*)d_in[6];
    const float* wv_s = (const float*)d_in[7];
    const float* wo_s = (const float*)d_in[8];
    const float* g_ca = (const float*)d_in[9];
    const float* wq_c = (const float*)d_in[10];
    const float* wk_c = (const float*)d_in[11];
    const float* wv_c = (const float*)d_in[12];
    const float* wo_c = (const float*)d_in[13];
    const float* g_m  = (const float*)d_in[14];
    const float* w1   = (const float*)d_in[15];
    const float* w2   = (const float*)d_in[16];
    float* out = (float*)d_out;

    const size_t OFF_KS = 4u * 1024 * 1024;
    const size_t OFF_VS = 8u * 1024 * 1024;
    const size_t OFF_KC = 12u * 1024 * 1024;
    const size_t OFF_VC = 16u * 1024 * 1024;

    char* ws = (char*)d_ws;
    const size_t MB = 1024 * 1024;
    bf16_t* wqkvTs = (bf16_t*)(ws + 0 * MB);   // [3072,1024]
    bf16_t* woTs   = (bf16_t*)(ws + 6 * MB);
    bf16_t* wqTc   = (bf16_t*)(ws + 8 * MB);
    bf16_t* wkvTc  = (bf16_t*)(ws + 10 * MB);  // [2048,1024]
    bf16_t* woTc   = (bf16_t*)(ws + 14 * MB);
    bf16_t* w1T    = (bf16_t*)(ws + 16 * MB);  // [4096,1024]
    bf16_t* w2T    = (bf16_t*)(ws + 24 * MB);  // [1024,4096]
    bf16_t* membf  = (bf16_t*)(ws + 32 * MB);  // [4096,1024]
    bf16_t* hbuf   = (bf16_t*)(ws + 40 * MB);  // [4096,1024]
    bf16_t* qbuf   = (bf16_t*)(ws + 48 * MB);  // [B,H,LT,HD]
    bf16_t* kbuf   = (bf16_t*)(ws + 56 * MB);  // [B,H,LS,HD]
    bf16_t* vbuf   = (bf16_t*)(ws + 64 * MB);  // [B,H,LS,HD]
    bf16_t* vTbuf  = (bf16_t*)(ws + 72 * MB);  // [B,H,HD,LS]
    bf16_t* Obuf   = (bf16_t*)(ws + 80 * MB);  // [B,LT,D]
    float*  attn_x  = (float*)(ws + 88 * MB);  // fp32 [4096,1024]
    float*  cross_x = (float*)(ws + 112 * MB); // fp32 [4096,1024]
    // FFN-phase overlays (attention buffers dead by then):
    bf16_t* ffnmid  = (bf16_t*)(ws + 48 * MB); // [4096,4096] bf16, 48..80
    float*  part    = (float*)(ws + 80 * MB);  // 2x fp32 [4096,1024], 80..112

    dim3 tb(32, 8);
    TPtrs tp;
    tp.in[0] = wq_s; tp.out[0] = wqkvTs;
    tp.in[1] = wk_s; tp.out[1] = wqkvTs + 1024 * 1024;
    tp.in[2] = wv_s; tp.out[2] = wqkvTs + 2 * 1024 * 1024;
    tp.in[3] = wo_s; tp.out[3] = woTs;
    tp.in[4] = wq_c; tp.out[4] = wqTc;
    tp.in[5] = wk_c; tp.out[5] = wkvTc;
    tp.in[6] = wv_c; tp.out[6] = wkvTc + 1024 * 1024;
    tp.in[7] = wo_c; tp.out[7] = woTc;
    transpose8_f2bf<<<dim3(32, 32, 8), tb, 0, stream>>>(tp);
    transpose_f2bf<<<dim3(128, 32), tb, 0, stream>>>(w1, w1T, DM, FF);
    transpose_f2bf<<<dim3(32, 128), tb, 0, stream>>>(w2, w2T, FF, DM);

    f2bf_kernel<<<4096, 256, 0, stream>>>(mem, membf, (size_t)BB * LS * DM);

    // ---- self-attention block ----
    rmsnorm_kernel<<<BB * LT, 256, 0, stream>>>(x, g_sa, hbuf);
    gemm_qkv<<<dim3(32, 24), 256, 0, stream>>>(
        hbuf, wqkvTs, 24, hbuf, wqkvTs, 0,
        qbuf, out + OFF_KS, kbuf, out + OFF_VS, vbuf);
    transpose_bf<<<dim3(32, 2, 64), tb, 0, stream>>>(vbuf, vTbuf);
    flash_attn<true><<<dim3(16, 64), 256, 0, stream>>>(qbuf, kbuf, vTbuf, nullptr, Obuf);
    gemm_bt<EP_RES, 1><<<dim3(32, 8), 256, 0, stream>>>(
        Obuf, woTs, 1024, 1024, attn_x, x, nullptr);

    // ---- cross-attention block ----
    rmsnorm_kernel<<<BB * LT, 256, 0, stream>>>(attn_x, g_ca, hbuf);
    gemm_qkv<<<dim3(32, 24), 256, 0, stream>>>(
        hbuf, wqTc, 8, membf, wkvTc, 1,
        qbuf, out + OFF_KC, kbuf, out + OFF_VC, vbuf);
    transpose_bf<<<dim3(32, 2, 64), tb, 0, stream>>>(vbuf, vTbuf);
    flash_attn<false><<<dim3(16, 64), 256, 0, stream>>>(qbuf, kbuf, vTbuf, pemb, Obuf);
    gemm_bt<EP_RES, 1><<<dim3(32, 8), 256, 0, stream>>>(
        Obuf, woTc, 1024, 1024, cross_x, attn_x, nullptr);

    // ---- FFN block ----
    rmsnorm_kernel<<<BB * LT, 256, 0, stream>>>(cross_x, g_m, hbuf);
    gemm_bt<EP_RELU, 1><<<dim3(32, 32), 256, 0, stream>>>(
        hbuf, w1T, 4096, 1024, nullptr, nullptr, ffnmid);
    gemm_bt<EP_PART, 2><<<dim3(32, 8, 2), 256, 0, stream>>>(
        ffnmid, w2T, 1024, 4096, part, nullptr, nullptr);
    reduce2_res<<<4096, 256, 0, stream>>>(part, cross_x, out);
}

// Round 2
// 600.346 us; speedup vs baseline: 1.0960x; 1.0306x over previous
//
#include <hip/hip_runtime.h>
#include <stdint.h>
#include <stddef.h>

// ---------- types ----------
typedef __bf16 bf16_t;
typedef __attribute__((ext_vector_type(8))) __bf16 bf16x8;
typedef __attribute__((ext_vector_type(4))) __bf16 bf16x4;
typedef __attribute__((ext_vector_type(4))) float f32x4;

#define LT 1024
#define LS 1024
#define DM 1024
#define NH 16
#define HD 64
#define FF 4096
#define BB 4

// async global->LDS, 16B per lane; LDS deposit = wave-uniform base + lane*16
__device__ __forceinline__ void gld_lds16(const bf16_t* g, bf16_t* l) {
    __builtin_amdgcn_global_load_lds(
        (const __attribute__((address_space(1))) void*)g,
        (__attribute__((address_space(3))) void*)l, 16, 0, 0);
}

// ---------- weight transpose fp32[R,C] -> bf16[C,R] ----------
__global__ __launch_bounds__(256) void transpose_f2bf(
    const float* __restrict__ in, bf16_t* __restrict__ out, int R, int C)
{
    __shared__ float tile[32][33];
    int bx = blockIdx.x * 32;
    int by = blockIdx.y * 32;
    int tx = threadIdx.x, ty = threadIdx.y;   // (32, 8)
#pragma unroll
    for (int j = 0; j < 4; j++)
        tile[ty + j * 8][tx] = in[(size_t)(by + ty + j * 8) * C + bx + tx];
    __syncthreads();
#pragma unroll
    for (int j = 0; j < 4; j++)
        out[(size_t)(bx + ty + j * 8) * R + by + tx] = (bf16_t)tile[tx][ty + j * 8];
}

// ---------- fused 8x 1024x1024 weight transposes (one launch) ----------
struct TPtrs { const float* in[8]; bf16_t* out[8]; };
__global__ __launch_bounds__(256) void transpose8_f2bf(TPtrs p)
{
    __shared__ float tile[32][33];
    const float* in = p.in[blockIdx.z];
    bf16_t* out = p.out[blockIdx.z];
    int bx = blockIdx.x * 32;
    int by = blockIdx.y * 32;
    int tx = threadIdx.x, ty = threadIdx.y;   // (32, 8)
#pragma unroll
    for (int j = 0; j < 4; j++)
        tile[ty + j * 8][tx] = in[(size_t)(by + ty + j * 8) * 1024 + bx + tx];
    __syncthreads();
#pragma unroll
    for (int j = 0; j < 4; j++)
        out[(size_t)(bx + ty + j * 8) * 1024 + by + tx] = (bf16_t)tile[tx][ty + j * 8];
}

// ---------- bf16 per-(b,h) transpose: [BH,L,HD] -> [BH,HD,L] ----------
__global__ __launch_bounds__(256) void transpose_bf(
    const bf16_t* __restrict__ in, bf16_t* __restrict__ out)
{
    __shared__ bf16_t tile[32][33];
    int bh = blockIdx.z;
    int r0 = blockIdx.x * 32;   // L dim
    int c0 = blockIdx.y * 32;   // HD dim
    const bf16_t* ib = in + (size_t)bh * LT * HD;
    bf16_t* ob = out + (size_t)bh * HD * LT;
    int tx = threadIdx.x, ty = threadIdx.y;
#pragma unroll
    for (int j = 0; j < 4; j++)
        tile[ty + j * 8][tx] = ib[(size_t)(r0 + ty + j * 8) * HD + c0 + tx];
    __syncthreads();
#pragma unroll
    for (int j = 0; j < 4; j++)
        ob[(size_t)(c0 + ty + j * 8) * LT + r0 + tx] = tile[tx][ty + j * 8];
}

// ---------- fp32 -> bf16 convert ----------
__global__ __launch_bounds__(256) void f2bf_kernel(
    const float* __restrict__ in, bf16_t* __restrict__ out, size_t n)
{
    size_t i = ((size_t)blockIdx.x * 256 + threadIdx.x) * 4;
    if (i + 3 < n) {
        float4 v = *(const float4*)&in[i];
        out[i + 0] = (bf16_t)v.x;
        out[i + 1] = (bf16_t)v.y;
        out[i + 2] = (bf16_t)v.z;
        out[i + 3] = (bf16_t)v.w;
    }
}

// ---------- split-K reduce + residual: out = p[0] + p[1] + res ----------
__global__ __launch_bounds__(256) void reduce2_res(
    const float* __restrict__ p, const float* __restrict__ res,
    float* __restrict__ out)
{
    const size_t MN = (size_t)BB * LT * DM;
    size_t i = ((size_t)blockIdx.x * 256 + threadIdx.x) * 4;
    float4 a = *(const float4*)&p[i];
    float4 b = *(const float4*)&p[i + MN];
    float4 r = *(const float4*)&res[i];
    float4 o;
    o.x = a.x + b.x + r.x; o.y = a.y + b.y + r.y;
    o.z = a.z + b.z + r.z; o.w = a.w + b.w + r.w;
    *(float4*)&out[i] = o;
}

// ---------- RMSNorm: fp32 row -> bf16 row ----------
__global__ __launch_bounds__(256) void rmsnorm_kernel(
    const float* __restrict__ x, const float* __restrict__ g,
    bf16_t* __restrict__ out)
{
    __shared__ float red[4];
    int row = blockIdx.x;
    int t = threadIdx.x;
    int lane = t & 63, w = t >> 6;
    const float* xr = x + (size_t)row * DM;
    float4 v = *(const float4*)&xr[t * 4];
    float ss = v.x * v.x + v.y * v.y + v.z * v.z + v.w * v.w;
#pragma unroll
    for (int off = 32; off > 0; off >>= 1) ss += __shfl_down(ss, off, 64);
    if (lane == 0) red[w] = ss;
    __syncthreads();
    float tot = red[0] + red[1] + red[2] + red[3];
    float inv = rsqrtf(tot * (1.0f / DM) + 1e-6f);
    float4 gv = *(const float4*)&g[t * 4];
    bf16_t* o = out + (size_t)row * DM + t * 4;
    o[0] = (bf16_t)(v.x * inv * gv.x);
    o[1] = (bf16_t)(v.y * inv * gv.y);
    o[2] = (bf16_t)(v.z * inv * gv.z);
    o[3] = (bf16_t)(v.w * inv * gv.w);
}

// ================= GEMM core (shared tile loop) =================
// acc += A[m0:m0+128, kBeg:kEnd] * Bt[n0:n0+128, kBeg:kEnd]^T
#define GEMM_BODY(Aptr, Btptr, Kstride, kBeg, kEnd)                              \
    for (int k0 = (kBeg); k0 < (kEnd); k0 += 64) {                               \
        __syncthreads();                                                         \
        _Pragma("unroll")                                                        \
        for (int i = 0; i < 4; i++) {                                            \
            int p = i * 256 + t;                                                 \
            int row = p >> 3;                                                    \
            int g = (p & 7) ^ (row & 7);                                         \
            gld_lds16(&(Aptr)[(size_t)(m0 + row) * (Kstride) + k0 + g * 8],      \
                      &lA[p * 8]);                                               \
            gld_lds16(&(Btptr)[(size_t)(n0 + row) * (Kstride) + k0 + g * 8],     \
                      &lB[p * 8]);                                               \
        }                                                                        \
        __syncthreads();                                                         \
        _Pragma("unroll")                                                        \
        for (int s = 0; s < 2; s++) {                                            \
            bf16x8 af[4], bfr[4];                                                \
            _Pragma("unroll")                                                    \
            for (int mt = 0; mt < 4; mt++) {                                     \
                int r = wr * 64 + mt * 16 + l15;                                 \
                af[mt] = *(const bf16x8*)&lA[((r << 3) + ((s * 4 + quad) ^ (r & 7))) << 3]; \
            }                                                                    \
            _Pragma("unroll")                                                    \
            for (int nt = 0; nt < 4; nt++) {                                     \
                int r = wc * 64 + nt * 16 + l15;                                 \
                bfr[nt] = *(const bf16x8*)&lB[((r << 3) + ((s * 4 + quad) ^ (r & 7))) << 3]; \
            }                                                                    \
            _Pragma("unroll")                                                    \
            for (int mt = 0; mt < 4; mt++)                                       \
                _Pragma("unroll")                                                \
                for (int nt = 0; nt < 4; nt++)                                   \
                    acc[mt][nt] = __builtin_amdgcn_mfma_f32_16x16x32_bf16(       \
                        af[mt], bfr[nt], acc[mt][nt], 0, 0, 0);                  \
        }                                                                        \
    }

// ---------- QKV projection GEMM (dual-source, head-layout epilogue) ----------
// grid.y < nb1 : A1*B1 (sections from secbase1); else A2*B2 (secbase2)
__global__ __launch_bounds__(256) void gemm_qkv(
    const bf16_t* __restrict__ A1, const bf16_t* __restrict__ B1, int nb1,
    const bf16_t* __restrict__ A2, const bf16_t* __restrict__ B2, int secbase2,
    bf16_t* __restrict__ qb,
    float* __restrict__ kF, bf16_t* __restrict__ kB,
    float* __restrict__ vF, bf16_t* __restrict__ vB)
{
    __shared__ bf16_t lA[128 * 64];
    __shared__ bf16_t lB[128 * 64];
    const int t = threadIdx.x;
    const int lane = t & 63, w = t >> 6;
    const int quad = lane >> 4, l15 = lane & 15;
    const int m0 = blockIdx.x * 128;
    const int wr = w >> 1, wc = w & 1;

    const bf16_t* A; const bf16_t* Bt; int n0, sec0;
    if ((int)blockIdx.y < nb1) { A = A1; Bt = B1; n0 = blockIdx.y * 128; sec0 = 0; }
    else { A = A2; Bt = B2; n0 = (blockIdx.y - nb1) * 128; sec0 = secbase2; }

    f32x4 acc[4][4] = {};
    GEMM_BODY(A, Bt, 1024, 0, 1024)

#pragma unroll
    for (int mt = 0; mt < 4; mt++) {
#pragma unroll
        for (int nt = 0; nt < 4; nt++) {
#pragma unroll
            for (int r = 0; r < 4; r++) {
                int row = m0 + wr * 64 + mt * 16 + quad * 4 + r;
                int col = n0 + wc * 64 + nt * 16 + l15;
                float v = acc[mt][nt][r];
                int b = row >> 10, tp = row & 1023;
                int sec = sec0 + (col >> 10);
                int c10 = col & 1023;
                int h = c10 >> 6, d = c10 & 63;
                size_t idx = (((size_t)(b * NH + h)) << 16) + (size_t)tp * HD + d;
                if (sec == 0) {
                    qb[idx] = (bf16_t)v;
                } else if (sec == 1) {
                    kF[idx] = v;
                    kB[idx] = (bf16_t)v;
                } else {
                    vF[idx] = v;
                    vB[idx] = (bf16_t)v;
                }
            }
        }
    }
}

// ---------- general GEMM: C[M,N] = A[M,K] * Bt[N,K]^T ----------
#define EP_RES 0    // fp32 store of (v + res)
#define EP_RELU 1   // bf16 relu store
#define EP_PART 2   // fp32 store to partial slice (split-K)

template <int EP, int KSPLIT>
__global__ __launch_bounds__(256) void gemm_bt(
    const bf16_t* __restrict__ A, const bf16_t* __restrict__ Bt,
    int N, int K,
    float* __restrict__ outF, const float* __restrict__ res,
    bf16_t* __restrict__ outB)
{
    __shared__ bf16_t lA[128 * 64];
    __shared__ bf16_t lB[128 * 64];
    const int t = threadIdx.x;
    const int lane = t & 63, w = t >> 6;
    const int quad = lane >> 4, l15 = lane & 15;
    const int m0 = blockIdx.x * 128, n0 = blockIdx.y * 128;
    const int wr = w >> 1, wc = w & 1;
    const int Kc = K / KSPLIT;
    const int kBeg = blockIdx.z * Kc;

    f32x4 acc[4][4] = {};
    GEMM_BODY(A, Bt, K, kBeg, kBeg + Kc)

    float* dst = outF;
    if constexpr (EP == EP_PART)
        dst = outF + (size_t)blockIdx.z * (size_t)gridDim.x * 128 * N;

#pragma unroll
    for (int mt = 0; mt < 4; mt++) {
#pragma unroll
        for (int nt = 0; nt < 4; nt++) {
#pragma unroll
            for (int r = 0; r < 4; r++) {
                int row = m0 + wr * 64 + mt * 16 + quad * 4 + r;
                int col = n0 + wc * 64 + nt * 16 + l15;
                float v = acc[mt][nt][r];
                if constexpr (EP == EP_RES) {
                    dst[(size_t)row * N + col] = v + res[(size_t)row * N + col];
                } else if constexpr (EP == EP_RELU) {
                    outB[(size_t)row * N + col] = (bf16_t)fmaxf(v, 0.0f);
                } else {
                    dst[(size_t)row * N + col] = v;
                }
            }
        }
    }
}

// ---------- flash attention ----------
// Swapped QK^T (S^T = mfma(K,Q)) puts each q-row's k-values mostly in-lane:
// row max/sum = 15 in-lane VALU + 2 shfl_xor (vs 4-deep swizzle chains x8).
// m_i/l_i are one scalar per lane (row = l15, replicated across quads).
// Defer-max (THR=8): skip alpha/rescale when max doesn't grow; P bounded by e^8.
// Double-buffered K/V staging with counted vmcnt; bias prefetched 1 tile ahead.
template <bool CAUSAL>
__global__ __launch_bounds__(256, 4) void flash_attn(
    const bf16_t* __restrict__ Q, const bf16_t* __restrict__ Kb,
    const bf16_t* __restrict__ Vt, const float* __restrict__ bias,
    bf16_t* __restrict__ O)
{
    __shared__ bf16_t lK[2][64 * 64];
    __shared__ bf16_t lV[2][64 * 64];
    __shared__ bf16_t lP[4][16 * 64];
    const int t = threadIdx.x;
    const int lane = t & 63, w = t >> 6;
    const int quad = lane >> 4, l15 = lane & 15;
    const int qt = blockIdx.x;
    const int yy = blockIdx.y;
    const int h = yy >> 2, b = yy & 3;       // batch-minor decode (bias L2 reuse)
    const int bhd = b * NH + h;
    const int q0 = qt * 64;

    const bf16_t* qbase = Q + (size_t)bhd * LT * HD;
    const bf16_t* kbase = Kb + (size_t)bhd * LS * HD;
    const bf16_t* vbase = Vt + (size_t)bhd * HD * LS;
    const float* bbase = bias + (size_t)h * LT * LS;   // unused when CAUSAL

    bf16x8 qf[2];
    const int qrow = q0 + w * 16 + l15;
#pragma unroll
    for (int s = 0; s < 2; s++)
        qf[s] = *(const bf16x8*)&qbase[(size_t)qrow * HD + s * 32 + quad * 8];

    f32x4 acc_o[4] = {};
    float m_i = -3.0e38f, l_i = 0.0f;   // per-lane; row = q0 + w*16 + l15

    const int nkt = CAUSAL ? (qt + 1) : (LS / 64);

    // ---- prologue: bias tile 0 loads first, then K/V staging (so the
    // bnxt-consuming wait at loop top leaves the gld_lds in flight) ----
    float bnxt[16], bcur[16];
    if constexpr (!CAUSAL) {
#pragma unroll
        for (int nt = 0; nt < 4; nt++)
#pragma unroll
            for (int r = 0; r < 4; r++)
                bnxt[nt * 4 + r] =
                    bbase[(size_t)qrow * LS + nt * 16 + quad * 4 + r];
    }
#pragma unroll
    for (int i = 0; i < 2; i++) {
        int p = i * 256 + t;
        int row = p >> 3;
        int g = (p & 7) ^ (row & 7);
        gld_lds16(&kbase[(size_t)row * HD + g * 8], &lK[0][p * 8]);
        gld_lds16(&vbase[(size_t)row * LS + g * 8], &lV[0][p * 8]);
    }

    for (int kt = 0; kt < nkt; kt++) {
        const int d = kt & 1;
        const int nxt = kt + 1;
        if constexpr (!CAUSAL) {
#pragma unroll
            for (int i = 0; i < 16; i++) bcur[i] = bnxt[i];
        }
        if (nxt < nkt) {
            const int nb = nxt * 64;
            const int nd = nxt & 1;
            if constexpr (!CAUSAL) {
#pragma unroll
                for (int nt = 0; nt < 4; nt++)
#pragma unroll
                    for (int r = 0; r < 4; r++)
                        bnxt[nt * 4 + r] =
                            bbase[(size_t)qrow * LS + nb + nt * 16 + quad * 4 + r];
            }
#pragma unroll
            for (int i = 0; i < 2; i++) {
                int p = i * 256 + t;
                int row = p >> 3;
                int g = (p & 7) ^ (row & 7);
                gld_lds16(&kbase[(size_t)(nb + row) * HD + g * 8], &lK[nd][p * 8]);
                gld_lds16(&vbase[(size_t)row * LS + nb + g * 8], &lV[nd][p * 8]);
            }
            if constexpr (!CAUSAL) {
                // newest 20 = 16 bias + 4 gld_lds for tile nxt; older must land
                asm volatile("s_waitcnt vmcnt(20)" ::: "memory");
            } else {
                asm volatile("s_waitcnt vmcnt(4)" ::: "memory");
            }
        } else {
            asm volatile("s_waitcnt vmcnt(0)" ::: "memory");
        }
        __builtin_amdgcn_s_barrier();
        __builtin_amdgcn_sched_barrier(0);   // keep LDS reads behind rendezvous

        const int kb = kt * 64;

        // ---- QK^T swapped: sacc[nt][r] = S[q=l15][k = kb + nt*16 + quad*4 + r]
        f32x4 sacc[4];
        __builtin_amdgcn_s_setprio(1);
#pragma unroll
        for (int nt = 0; nt < 4; nt++) {
            f32x4 sa = {};
#pragma unroll
            for (int s = 0; s < 2; s++) {
                int r = nt * 16 + l15;
                bf16x8 kf = *(const bf16x8*)&lK[d][((r << 3) + ((s * 4 + quad) ^ (r & 7))) << 3];
                sa = __builtin_amdgcn_mfma_f32_16x16x32_bf16(kf, qf[s], sa, 0, 0, 0);
            }
            sacc[nt] = sa;
        }
        __builtin_amdgcn_s_setprio(0);

        // ---- scale + bias/mask; balanced in-lane max ----
        float sval[4][4];
        float tmn[4];
#pragma unroll
        for (int nt = 0; nt < 4; nt++) {
#pragma unroll
            for (int r = 0; r < 4; r++) {
                float v = sacc[nt][r] * 0.125f;
                if constexpr (CAUSAL) {
                    int col = kb + nt * 16 + quad * 4 + r;
                    if (col > qrow) v = -1e9f;
                } else {
                    v += bcur[nt * 4 + r];
                }
                sval[nt][r] = v;
            }
            tmn[nt] = fmaxf(fmaxf(sval[nt][0], sval[nt][1]),
                            fmaxf(sval[nt][2], sval[nt][3]));
        }
        float tm = fmaxf(fmaxf(tmn[0], tmn[1]), fmaxf(tmn[2], tmn[3]));
        tm = fmaxf(tm, __shfl_xor(tm, 16, 64));
        tm = fmaxf(tm, __shfl_xor(tm, 32, 64));

        // ---- defer-max: rescale only when the running max actually grows ----
        if (!__all(tm <= m_i + 8.0f)) {
            float mn = fmaxf(m_i, tm);
            float alpha = __expf(m_i - mn);
            m_i = mn;
            l_i *= alpha;
            float ar[4];
#pragma unroll
            for (int r = 0; r < 4; r++) ar[r] = __shfl(alpha, quad * 4 + r, 64);
#pragma unroll
            for (int dt = 0; dt < 4; dt++)
#pragma unroll
                for (int r = 0; r < 4; r++) acc_o[dt][r] *= ar[r];
        }

        // ---- exp, row-sum, pack P (4 bf16 = 8B per nt -> ds_write_b64) ----
        float rs[4];
#pragma unroll
        for (int nt = 0; nt < 4; nt++) {
            float p0 = __expf(sval[nt][0] - m_i);
            float p1 = __expf(sval[nt][1] - m_i);
            float p2 = __expf(sval[nt][2] - m_i);
            float p3 = __expf(sval[nt][3] - m_i);
            rs[nt] = (p0 + p1) + (p2 + p3);
            bf16x4 pk;
            pk[0] = (bf16_t)p0; pk[1] = (bf16_t)p1;
            pk[2] = (bf16_t)p2; pk[3] = (bf16_t)p3;
            int gc = nt * 2 + (quad >> 1);
            int eoff = ((l15 << 3) + (gc ^ (l15 & 7))) * 8 + (quad & 1) * 4;
            *(bf16x4*)&lP[w][eoff] = pk;
        }
        float rsum = (rs[0] + rs[1]) + (rs[2] + rs[3]);
        rsum += __shfl_xor(rsum, 16, 64);
        rsum += __shfl_xor(rsum, 32, 64);
        l_i += rsum;

        // ---- PV ----
#pragma unroll
        for (int s = 0; s < 2; s++) {
            bf16x8 pf = *(const bf16x8*)&lP[w][((l15 << 3) + ((s * 4 + quad) ^ (l15 & 7))) << 3];
            __builtin_amdgcn_s_setprio(1);
#pragma unroll
            for (int dt = 0; dt < 4; dt++) {
                int r = dt * 16 + l15;
                bf16x8 vf = *(const bf16x8*)&lV[d][((r << 3) + ((s * 4 + quad) ^ (r & 7))) << 3];
                acc_o[dt] = __builtin_amdgcn_mfma_f32_16x16x32_bf16(pf, vf, acc_o[dt], 0, 0, 0);
            }
            __builtin_amdgcn_s_setprio(0);
        }
        __builtin_amdgcn_s_barrier();   // all reads of buf[d] done before restage
    }

    // ---- epilogue: redistribute l_i (row=l15 layout) to acc rows ----
    float lr[4];
#pragma unroll
    for (int r = 0; r < 4; r++) lr[r] = __shfl(l_i, quad * 4 + r, 64);
#pragma unroll
    for (int dt = 0; dt < 4; dt++) {
#pragma unroll
        for (int r = 0; r < 4; r++) {
            int row = q0 + w * 16 + quad * 4 + r;
            int col = h * HD + dt * 16 + l15;
            float v = acc_o[dt][r] / lr[r];
            O[((size_t)(b * LT + row)) * DM + col] = (bf16_t)v;
        }
    }
}

// ---------- host ----------
extern "C" void kernel_launch(void* const* d_in, const int* in_sizes, int n_in,
                              void* d_out, int out_size, void* d_ws, size_t ws_size,
                              hipStream_t stream)
{
    (void)in_sizes; (void)n_in; (void)out_size; (void)ws_size;
    const float* x    = (const float*)d_in[0];
    const float* mem  = (const float*)d_in[1];
    const float* pemb = (const float*)d_in[2];
    const float* g_sa = (const float*)d_in[4];
    const float* wq_s = (const float*)d_in[5];
    const float* wk_s = (const float*)d_in[6];
    const float* wv_s = (const float*)d_in[7];
    const float* wo_s = (const float*)d_in[8];
    const float* g_ca = (const float*)d_in[9];
    const float* wq_c = (const float*)d_in[10];
    const float* wk_c = (const float*)d_in[11];
    const float* wv_c = (const float*)d_in[12];
    const float* wo_c = (const float*)d_in[13];
    const float* g_m  = (const float*)d_in[14];
    const float* w1   = (const float*)d_in[15];
    const float* w2   = (const float*)d_in[16];
    float* out = (float*)d_out;

    const size_t OFF_KS = 4u * 1024 * 1024;
    const size_t OFF_VS = 8u * 1024 * 1024;
    const size_t OFF_KC = 12u * 1024 * 1024;
    const size_t OFF_VC = 16u * 1024 * 1024;

    char* ws = (char*)d_ws;
    const size_t MB = 1024 * 1024;
    bf16_t* wqkvTs = (bf16_t*)(ws + 0 * MB);   // [3072,1024]
    bf16_t* woTs   = (bf16_t*)(ws + 6 * MB);
    bf16_t* wqTc   = (bf16_t*)(ws + 8 * MB);
    bf16_t* wkvTc  = (bf16_t*)(ws + 10 * MB);  // [2048,1024]
    bf16_t* woTc   = (bf16_t*)(ws + 14 * MB);
    bf16_t* w1T    = (bf16_t*)(ws + 16 * MB);  // [4096,1024]
    bf16_t* w2T    = (bf16_t*)(ws + 24 * MB);  // [1024,4096]
    bf16_t* membf  = (bf16_t*)(ws + 32 * MB);  // [4096,1024]
    bf16_t* hbuf   = (bf16_t*)(ws + 40 * MB);  // [4096,1024]
    bf16_t* qbuf   = (bf16_t*)(ws + 48 * MB);  // [B,H,LT,HD]
    bf16_t* kbuf   = (bf16_t*)(ws + 56 * MB);  // [B,H,LS,HD]
    bf16_t* vbuf   = (bf16_t*)(ws + 64 * MB);  // [B,H,LS,HD]
    bf16_t* vTbuf  = (bf16_t*)(ws + 72 * MB);  // [B,H,HD,LS]
    bf16_t* Obuf   = (bf16_t*)(ws + 80 * MB);  // [B,LT,D]
    float*  attn_x  = (float*)(ws + 88 * MB);  // fp32 [4096,1024]
    float*  cross_x = (float*)(ws + 112 * MB); // fp32 [4096,1024]
    // FFN-phase overlays (attention buffers dead by then):
    bf16_t* ffnmid  = (bf16_t*)(ws + 48 * MB); // [4096,4096] bf16, 48..80
    float*  part    = (float*)(ws + 80 * MB);  // 2x fp32 [4096,1024], 80..112

    dim3 tb(32, 8);
    TPtrs tp;
    tp.in[0] = wq_s; tp.out[0] = wqkvTs;
    tp.in[1] = wk_s; tp.out[1] = wqkvTs + 1024 * 1024;
    tp.in[2] = wv_s; tp.out[2] = wqkvTs + 2 * 1024 * 1024;
    tp.in[3] = wo_s; tp.out[3] = woTs;
    tp.in[4] = wq_c; tp.out[4] = wqTc;
    tp.in[5] = wk_c; tp.out[5] = wkvTc;
    tp.in[6] = wv_c; tp.out[6] = wkvTc + 1024 * 1024;
    tp.in[7] = wo_c; tp.out[7] = woTc;
    transpose8_f2bf<<<dim3(32, 32, 8), tb, 0, stream>>>(tp);
    transpose_f2bf<<<dim3(128, 32), tb, 0, stream>>>(w1, w1T, DM, FF);
    transpose_f2bf<<<dim3(32, 128), tb, 0, stream>>>(w2, w2T, FF, DM);

    f2bf_kernel<<<4096, 256, 0, stream>>>(mem, membf, (size_t)BB * LS * DM);

    // ---- self-attention block ----
    rmsnorm_kernel<<<BB * LT, 256, 0, stream>>>(x, g_sa, hbuf);
    gemm_qkv<<<dim3(32, 24), 256, 0, stream>>>(
        hbuf, wqkvTs, 24, hbuf, wqkvTs, 0,
        qbuf, out + OFF_KS, kbuf, out + OFF_VS, vbuf);
    transpose_bf<<<dim3(32, 2, 64), tb, 0, stream>>>(vbuf, vTbuf);
    flash_attn<true><<<dim3(16, 64), 256, 0, stream>>>(qbuf, kbuf, vTbuf, nullptr, Obuf);
    gemm_bt<EP_RES, 1><<<dim3(32, 8), 256, 0, stream>>>(
        Obuf, woTs, 1024, 1024, attn_x, x, nullptr);

    // ---- cross-attention block ----
    rmsnorm_kernel<<<BB * LT, 256, 0, stream>>>(attn_x, g_ca, hbuf);
    gemm_qkv<<<dim3(32, 24), 256, 0, stream>>>(
        hbuf, wqTc, 8, membf, wkvTc, 1,
        qbuf, out + OFF_KC, kbuf, out + OFF_VC, vbuf);
    transpose_bf<<<dim3(32, 2, 64), tb, 0, stream>>>(vbuf, vTbuf);
    flash_attn<false><<<dim3(16, 64), 256, 0, stream>>>(qbuf, kbuf, vTbuf, pemb, Obuf);
    gemm_bt<EP_RES, 1><<<dim3(32, 8), 256, 0, stream>>>(
        Obuf, woTc, 1024, 1024, cross_x, attn_x, nullptr);

    // ---- FFN block ----
    rmsnorm_kernel<<<BB * LT, 256, 0, stream>>>(cross_x, g_m, hbuf);
    gemm_bt<EP_RELU, 1><<<dim3(32, 32), 256, 0, stream>>>(
        hbuf, w1T, 4096, 1024, nullptr, nullptr, ffnmid);
    gemm_bt<EP_PART, 2><<<dim3(32, 8, 2), 256, 0, stream>>>(
        ffnmid, w2T, 1024, 4096, part, nullptr, nullptr);
    reduce2_res<<<4096, 256, 0, stream>>>(part, cross_x, out);
}

// Round 3
// 591.176 us; speedup vs baseline: 1.1130x; 1.0155x over previous
//
#include <hip/hip_runtime.h>
#include <stdint.h>
#include <stddef.h>

// ---------- types ----------
typedef __bf16 bf16_t;
typedef __attribute__((ext_vector_type(8))) __bf16 bf16x8;
typedef __attribute__((ext_vector_type(4))) __bf16 bf16x4;
typedef __attribute__((ext_vector_type(4))) float f32x4;

#define LT 1024
#define LS 1024
#define DM 1024
#define NH 16
#define HD 64
#define FF 4096
#define BB 4

#define LOG2E 1.4426950408889634f

#if __has_builtin(__builtin_amdgcn_exp2f)
#define EXP2F(x) __builtin_amdgcn_exp2f(x)
#else
#define EXP2F(x) exp2f(x)
#endif
#if __has_builtin(__builtin_amdgcn_rcpf)
#define RCPF(x) __builtin_amdgcn_rcpf(x)
#else
#define RCPF(x) (1.0f / (x))
#endif

// async global->LDS, 16B per lane; LDS deposit = wave-uniform base + lane*16
__device__ __forceinline__ void gld_lds16(const bf16_t* g, bf16_t* l) {
    __builtin_amdgcn_global_load_lds(
        (const __attribute__((address_space(1))) void*)g,
        (__attribute__((address_space(3))) void*)l, 16, 0, 0);
}

// ---------- weight transpose fp32[R,C] -> bf16[C,R] ----------
__global__ __launch_bounds__(256) void transpose_f2bf(
    const float* __restrict__ in, bf16_t* __restrict__ out, int R, int C)
{
    __shared__ float tile[32][33];
    int bx = blockIdx.x * 32;
    int by = blockIdx.y * 32;
    int tx = threadIdx.x, ty = threadIdx.y;   // (32, 8)
#pragma unroll
    for (int j = 0; j < 4; j++)
        tile[ty + j * 8][tx] = in[(size_t)(by + ty + j * 8) * C + bx + tx];
    __syncthreads();
#pragma unroll
    for (int j = 0; j < 4; j++)
        out[(size_t)(bx + ty + j * 8) * R + by + tx] = (bf16_t)tile[tx][ty + j * 8];
}

// ---------- fused 8x 1024x1024 weight transposes (one launch) ----------
struct TPtrs { const float* in[8]; bf16_t* out[8]; };
__global__ __launch_bounds__(256) void transpose8_f2bf(TPtrs p)
{
    __shared__ float tile[32][33];
    const float* in = p.in[blockIdx.z];
    bf16_t* out = p.out[blockIdx.z];
    int bx = blockIdx.x * 32;
    int by = blockIdx.y * 32;
    int tx = threadIdx.x, ty = threadIdx.y;   // (32, 8)
#pragma unroll
    for (int j = 0; j < 4; j++)
        tile[ty + j * 8][tx] = in[(size_t)(by + ty + j * 8) * 1024 + bx + tx];
    __syncthreads();
#pragma unroll
    for (int j = 0; j < 4; j++)
        out[(size_t)(bx + ty + j * 8) * 1024 + by + tx] = (bf16_t)tile[tx][ty + j * 8];
}

// ---------- bf16 per-(b,h) transpose: [BH,L,HD] -> [BH,HD,L] ----------
__global__ __launch_bounds__(256) void transpose_bf(
    const bf16_t* __restrict__ in, bf16_t* __restrict__ out)
{
    __shared__ bf16_t tile[32][33];
    int bh = blockIdx.z;
    int r0 = blockIdx.x * 32;   // L dim
    int c0 = blockIdx.y * 32;   // HD dim
    const bf16_t* ib = in + (size_t)bh * LT * HD;
    bf16_t* ob = out + (size_t)bh * HD * LT;
    int tx = threadIdx.x, ty = threadIdx.y;
#pragma unroll
    for (int j = 0; j < 4; j++)
        tile[ty + j * 8][tx] = ib[(size_t)(r0 + ty + j * 8) * HD + c0 + tx];
    __syncthreads();
#pragma unroll
    for (int j = 0; j < 4; j++)
        ob[(size_t)(c0 + ty + j * 8) * LT + r0 + tx] = tile[tx][ty + j * 8];
}

// ---------- fp32 -> bf16 convert ----------
__global__ __launch_bounds__(256) void f2bf_kernel(
    const float* __restrict__ in, bf16_t* __restrict__ out, size_t n)
{
    size_t i = ((size_t)blockIdx.x * 256 + threadIdx.x) * 4;
    if (i + 3 < n) {
        float4 v = *(const float4*)&in[i];
        out[i + 0] = (bf16_t)v.x;
        out[i + 1] = (bf16_t)v.y;
        out[i + 2] = (bf16_t)v.z;
        out[i + 3] = (bf16_t)v.w;
    }
}

// ---------- split-K reduce + residual: out = p[0] + p[1] + res ----------
__global__ __launch_bounds__(256) void reduce2_res(
    const float* __restrict__ p, const float* __restrict__ res,
    float* __restrict__ out)
{
    const size_t MN = (size_t)BB * LT * DM;
    size_t i = ((size_t)blockIdx.x * 256 + threadIdx.x) * 4;
    float4 a = *(const float4*)&p[i];
    float4 b = *(const float4*)&p[i + MN];
    float4 r = *(const float4*)&res[i];
    float4 o;
    o.x = a.x + b.x + r.x; o.y = a.y + b.y + r.y;
    o.z = a.z + b.z + r.z; o.w = a.w + b.w + r.w;
    *(float4*)&out[i] = o;
}

// ---------- RMSNorm: fp32 row -> bf16 row ----------
__global__ __launch_bounds__(256) void rmsnorm_kernel(
    const float* __restrict__ x, const float* __restrict__ g,
    bf16_t* __restrict__ out)
{
    __shared__ float red[4];
    int row = blockIdx.x;
    int t = threadIdx.x;
    int lane = t & 63, w = t >> 6;
    const float* xr = x + (size_t)row * DM;
    float4 v = *(const float4*)&xr[t * 4];
    float ss = v.x * v.x + v.y * v.y + v.z * v.z + v.w * v.w;
#pragma unroll
    for (int off = 32; off > 0; off >>= 1) ss += __shfl_down(ss, off, 64);
    if (lane == 0) red[w] = ss;
    __syncthreads();
    float tot = red[0] + red[1] + red[2] + red[3];
    float inv = rsqrtf(tot * (1.0f / DM) + 1e-6f);
    float4 gv = *(const float4*)&g[t * 4];
    bf16_t* o = out + (size_t)row * DM + t * 4;
    o[0] = (bf16_t)(v.x * inv * gv.x);
    o[1] = (bf16_t)(v.y * inv * gv.y);
    o[2] = (bf16_t)(v.z * inv * gv.z);
    o[3] = (bf16_t)(v.w * inv * gv.w);
}

// ================= GEMM core (shared tile loop) =================
// acc += A[m0:m0+128, kBeg:kEnd] * Bt[n0:n0+128, kBeg:kEnd]^T
#define GEMM_BODY(Aptr, Btptr, Kstride, kBeg, kEnd)                              \
    for (int k0 = (kBeg); k0 < (kEnd); k0 += 64) {                               \
        __syncthreads();                                                         \
        _Pragma("unroll")                                                        \
        for (int i = 0; i < 4; i++) {                                            \
            int p = i * 256 + t;                                                 \
            int row = p >> 3;                                                    \
            int g = (p & 7) ^ (row & 7);                                         \
            gld_lds16(&(Aptr)[(size_t)(m0 + row) * (Kstride) + k0 + g * 8],      \
                      &lA[p * 8]);                                               \
            gld_lds16(&(Btptr)[(size_t)(n0 + row) * (Kstride) + k0 + g * 8],     \
                      &lB[p * 8]);                                               \
        }                                                                        \
        __syncthreads();                                                         \
        _Pragma("unroll")                                                        \
        for (int s = 0; s < 2; s++) {                                            \
            bf16x8 af[4], bfr[4];                                                \
            _Pragma("unroll")                                                    \
            for (int mt = 0; mt < 4; mt++) {                                     \
                int r = wr * 64 + mt * 16 + l15;                                 \
                af[mt] = *(const bf16x8*)&lA[((r << 3) + ((s * 4 + quad) ^ (r & 7))) << 3]; \
            }                                                                    \
            _Pragma("unroll")                                                    \
            for (int nt = 0; nt < 4; nt++) {                                     \
                int r = wc * 64 + nt * 16 + l15;                                 \
                bfr[nt] = *(const bf16x8*)&lB[((r << 3) + ((s * 4 + quad) ^ (r & 7))) << 3]; \
            }                                                                    \
            _Pragma("unroll")                                                    \
            for (int mt = 0; mt < 4; mt++)                                       \
                _Pragma("unroll")                                                \
                for (int nt = 0; nt < 4; nt++)                                   \
                    acc[mt][nt] = __builtin_amdgcn_mfma_f32_16x16x32_bf16(       \
                        af[mt], bfr[nt], acc[mt][nt], 0, 0, 0);                  \
        }                                                                        \
    }

// ---------- QKV projection GEMM (dual-source, head-layout epilogue) ----------
// grid.y < nb1 : A1*B1 (sections from secbase1); else A2*B2 (secbase2)
// Q (sec==0) is pre-scaled by 0.125*log2(e) so flash softmax runs in exp2 domain.
__global__ __launch_bounds__(256) void gemm_qkv(
    const bf16_t* __restrict__ A1, const bf16_t* __restrict__ B1, int nb1,
    const bf16_t* __restrict__ A2, const bf16_t* __restrict__ B2, int secbase2,
    bf16_t* __restrict__ qb,
    float* __restrict__ kF, bf16_t* __restrict__ kB,
    float* __restrict__ vF, bf16_t* __restrict__ vB)
{
    __shared__ bf16_t lA[128 * 64];
    __shared__ bf16_t lB[128 * 64];
    const int t = threadIdx.x;
    const int lane = t & 63, w = t >> 6;
    const int quad = lane >> 4, l15 = lane & 15;
    const int m0 = blockIdx.x * 128;
    const int wr = w >> 1, wc = w & 1;

    const bf16_t* A; const bf16_t* Bt; int n0, sec0;
    if ((int)blockIdx.y < nb1) { A = A1; Bt = B1; n0 = blockIdx.y * 128; sec0 = 0; }
    else { A = A2; Bt = B2; n0 = (blockIdx.y - nb1) * 128; sec0 = secbase2; }

    f32x4 acc[4][4] = {};
    GEMM_BODY(A, Bt, 1024, 0, 1024)

#pragma unroll
    for (int mt = 0; mt < 4; mt++) {
#pragma unroll
        for (int nt = 0; nt < 4; nt++) {
#pragma unroll
            for (int r = 0; r < 4; r++) {
                int row = m0 + wr * 64 + mt * 16 + quad * 4 + r;
                int col = n0 + wc * 64 + nt * 16 + l15;
                float v = acc[mt][nt][r];
                int b = row >> 10, tp = row & 1023;
                int sec = sec0 + (col >> 10);
                int c10 = col & 1023;
                int h = c10 >> 6, d = c10 & 63;
                size_t idx = (((size_t)(b * NH + h)) << 16) + (size_t)tp * HD + d;
                if (sec == 0) {
                    qb[idx] = (bf16_t)(v * (0.125f * LOG2E));
                } else if (sec == 1) {
                    kF[idx] = v;
                    kB[idx] = (bf16_t)v;
                } else {
                    vF[idx] = v;
                    vB[idx] = (bf16_t)v;
                }
            }
        }
    }
}

// ---------- general GEMM: C[M,N] = A[M,K] * Bt[N,K]^T ----------
#define EP_RES 0    // fp32 store of (v + res)
#define EP_RELU 1   // bf16 relu store
#define EP_PART 2   // fp32 store to partial slice (split-K)

template <int EP, int KSPLIT>
__global__ __launch_bounds__(256) void gemm_bt(
    const bf16_t* __restrict__ A, const bf16_t* __restrict__ Bt,
    int N, int K,
    float* __restrict__ outF, const float* __restrict__ res,
    bf16_t* __restrict__ outB)
{
    __shared__ bf16_t lA[128 * 64];
    __shared__ bf16_t lB[128 * 64];
    const int t = threadIdx.x;
    const int lane = t & 63, w = t >> 6;
    const int quad = lane >> 4, l15 = lane & 15;
    const int m0 = blockIdx.x * 128, n0 = blockIdx.y * 128;
    const int wr = w >> 1, wc = w & 1;
    const int Kc = K / KSPLIT;
    const int kBeg = blockIdx.z * Kc;

    f32x4 acc[4][4] = {};
    GEMM_BODY(A, Bt, K, kBeg, kBeg + Kc)

    float* dst = outF;
    if constexpr (EP == EP_PART)
        dst = outF + (size_t)blockIdx.z * (size_t)gridDim.x * 128 * N;

#pragma unroll
    for (int mt = 0; mt < 4; mt++) {
#pragma unroll
        for (int nt = 0; nt < 4; nt++) {
#pragma unroll
            for (int r = 0; r < 4; r++) {
                int row = m0 + wr * 64 + mt * 16 + quad * 4 + r;
                int col = n0 + wc * 64 + nt * 16 + l15;
                float v = acc[mt][nt][r];
                if constexpr (EP == EP_RES) {
                    dst[(size_t)row * N + col] = v + res[(size_t)row * N + col];
                } else if constexpr (EP == EP_RELU) {
                    outB[(size_t)row * N + col] = (bf16_t)fmaxf(v, 0.0f);
                } else {
                    dst[(size_t)row * N + col] = v;
                }
            }
        }
    }
}

// ---------- flash attention ----------
// Swapped QK^T (S^T = mfma(K,Q)); softmax in exp2 domain (Q pre-scaled by
// 0.125*log2e in projection). Common path has ZERO cross-lane ops:
//  - defer-max triggered from per-lane PARTIAL max (identical condition)
//  - l_i kept as per-lane partial sum; cross-quad reduce once at epilogue
// lP writes use (l15>>3)-XOR on the sub-chunk -> conflict-free b64 writes;
// reads use 2x b64 with matching XOR. Double-buffered K/V via counted vmcnt.
template <bool CAUSAL>
__global__ __launch_bounds__(256, 4) void flash_attn(
    const bf16_t* __restrict__ Q, const bf16_t* __restrict__ Kb,
    const bf16_t* __restrict__ Vt, const float* __restrict__ bias,
    bf16_t* __restrict__ O)
{
    __shared__ bf16_t lK[2][64 * 64];
    __shared__ bf16_t lV[2][64 * 64];
    __shared__ bf16_t lP[4][16 * 64];
    const int t = threadIdx.x;
    const int lane = t & 63, w = t >> 6;
    const int quad = lane >> 4, l15 = lane & 15;
    const int xr8 = l15 & 7, xb = l15 >> 3;
    const int qt = blockIdx.x;
    const int yy = blockIdx.y;
    const int h = yy >> 2, b = yy & 3;       // batch-minor decode (bias L2 reuse)
    const int bhd = b * NH + h;
    const int q0 = qt * 64;

    const bf16_t* qbase = Q + (size_t)bhd * LT * HD;
    const bf16_t* kbase = Kb + (size_t)bhd * LS * HD;
    const bf16_t* vbase = Vt + (size_t)bhd * HD * LS;
    const float* bbase = bias + (size_t)h * LT * LS;   // unused when CAUSAL

    bf16x8 qf[2];
    const int qrow = q0 + w * 16 + l15;
#pragma unroll
    for (int s = 0; s < 2; s++)
        qf[s] = *(const bf16x8*)&qbase[(size_t)qrow * HD + s * 32 + quad * 8];

    f32x4 acc_o[4] = {};
    float m2 = -3.0e38f;   // running max, log2 domain, row-uniform (row = l15)
    float lp = 0.0f;       // PARTIAL row sum (this lane's k-subset only)

    const int nkt = CAUSAL ? (qt + 1) : (LS / 64);

    // ---- prologue: bias tile 0 loads first, then K/V staging ----
    float bnxt[16], bcur[16];
    if constexpr (!CAUSAL) {
#pragma unroll
        for (int nt = 0; nt < 4; nt++)
#pragma unroll
            for (int r = 0; r < 4; r++)
                bnxt[nt * 4 + r] =
                    bbase[(size_t)qrow * LS + nt * 16 + quad * 4 + r];
    }
#pragma unroll
    for (int i = 0; i < 2; i++) {
        int p = i * 256 + t;
        int row = p >> 3;
        int g = (p & 7) ^ (row & 7);
        gld_lds16(&kbase[(size_t)row * HD + g * 8], &lK[0][p * 8]);
        gld_lds16(&vbase[(size_t)row * LS + g * 8], &lV[0][p * 8]);
    }

    for (int kt = 0; kt < nkt; kt++) {
        const int d = kt & 1;
        const int nxt = kt + 1;
        if constexpr (!CAUSAL) {
#pragma unroll
            for (int i = 0; i < 16; i++) bcur[i] = bnxt[i];
        }
        if (nxt < nkt) {
            const int nb = nxt * 64;
            const int nd = nxt & 1;
            if constexpr (!CAUSAL) {
#pragma unroll
                for (int nt = 0; nt < 4; nt++)
#pragma unroll
                    for (int r = 0; r < 4; r++)
                        bnxt[nt * 4 + r] =
                            bbase[(size_t)qrow * LS + nb + nt * 16 + quad * 4 + r];
            }
#pragma unroll
            for (int i = 0; i < 2; i++) {
                int p = i * 256 + t;
                int row = p >> 3;
                int g = (p & 7) ^ (row & 7);
                gld_lds16(&kbase[(size_t)(nb + row) * HD + g * 8], &lK[nd][p * 8]);
                gld_lds16(&vbase[(size_t)row * LS + nb + g * 8], &lV[nd][p * 8]);
            }
            if constexpr (!CAUSAL) {
                // newest 20 = 16 bias + 4 gld_lds for tile nxt; older must land
                asm volatile("s_waitcnt vmcnt(20)" ::: "memory");
            } else {
                asm volatile("s_waitcnt vmcnt(4)" ::: "memory");
            }
        } else {
            asm volatile("s_waitcnt vmcnt(0)" ::: "memory");
        }
        __builtin_amdgcn_s_barrier();
        __builtin_amdgcn_sched_barrier(0);   // keep LDS reads behind rendezvous

        // ---- QK^T swapped: sacc[nt][r] = S2[q=l15][k = kt*64 + nt*16 + quad*4 + r]
        f32x4 sacc[4];
        __builtin_amdgcn_s_setprio(1);
#pragma unroll
        for (int nt = 0; nt < 4; nt++) {
            f32x4 sa = {};
#pragma unroll
            for (int s = 0; s < 2; s++) {
                int r = nt * 16 + l15;
                bf16x8 kf = *(const bf16x8*)&lK[d][((r << 3) + ((s * 4 + quad) ^ (r & 7))) << 3];
                sa = __builtin_amdgcn_mfma_f32_16x16x32_bf16(kf, qf[s], sa, 0, 0, 0);
            }
            sacc[nt] = sa;
        }
        __builtin_amdgcn_s_setprio(0);

        // ---- sval (log2 domain) + per-lane partial max ----
        float sval[4][4];
        float tmn[4];
#pragma unroll
        for (int nt = 0; nt < 4; nt++) {
#pragma unroll
            for (int r = 0; r < 4; r++) {
                float v = sacc[nt][r];
                if constexpr (CAUSAL) {
                    if (kt == nkt - 1) {    // only diagonal tile needs masking
                        int col = kt * 64 + nt * 16 + quad * 4 + r;
                        if (col > qrow) v = -1e9f;
                    }
                } else {
                    v = fmaf(bcur[nt * 4 + r], LOG2E, v);
                }
                sval[nt][r] = v;
            }
            tmn[nt] = fmaxf(fmaxf(sval[nt][0], sval[nt][1]),
                            fmaxf(sval[nt][2], sval[nt][3]));
        }
        float pm = fmaxf(fmaxf(tmn[0], tmn[1]), fmaxf(tmn[2], tmn[3]));

        // ---- defer-max on PARTIAL max (same condition as full max) ----
        if (!__all(pm <= m2 + 11.5f)) {
            float tm = pm;
            tm = fmaxf(tm, __shfl_xor(tm, 16, 64));
            tm = fmaxf(tm, __shfl_xor(tm, 32, 64));
            float mn = fmaxf(m2, tm);
            float alpha = EXP2F(m2 - mn);
            m2 = mn;
            lp *= alpha;
            float ar[4];
#pragma unroll
            for (int r = 0; r < 4; r++) ar[r] = __shfl(alpha, quad * 4 + r, 64);
#pragma unroll
            for (int dt = 0; dt < 4; dt++)
#pragma unroll
                for (int r = 0; r < 4; r++) acc_o[dt][r] *= ar[r];
        }

        // ---- exp2, partial row-sum, pack P -> conflict-free b64 writes ----
#pragma unroll
        for (int nt = 0; nt < 4; nt++) {
            float p0 = EXP2F(sval[nt][0] - m2);
            float p1 = EXP2F(sval[nt][1] - m2);
            float p2 = EXP2F(sval[nt][2] - m2);
            float p3 = EXP2F(sval[nt][3] - m2);
            lp += (p0 + p1) + (p2 + p3);
            bf16x4 pk;
            pk[0] = (bf16_t)p0; pk[1] = (bf16_t)p1;
            pk[2] = (bf16_t)p2; pk[3] = (bf16_t)p3;
            int gc = nt * 2 + (quad >> 1);
            int pos = ((gc ^ xr8) << 3) + (((quad & 1) ^ xb) << 2);
            *(bf16x4*)&lP[w][(l15 << 6) + pos] = pk;
        }

        // ---- PV ----
#pragma unroll
        for (int s = 0; s < 2; s++) {
            int gbase = (l15 << 6) + (((s * 4 + quad) ^ xr8) << 3);
            bf16x4 plo = *(const bf16x4*)&lP[w][gbase + ((0 ^ xb) << 2)];
            bf16x4 phi = *(const bf16x4*)&lP[w][gbase + ((1 ^ xb) << 2)];
            bf16x8 pf = __builtin_shufflevector(plo, phi, 0, 1, 2, 3, 4, 5, 6, 7);
            __builtin_amdgcn_s_setprio(1);
#pragma unroll
            for (int dt = 0; dt < 4; dt++) {
                int r = dt * 16 + l15;
                bf16x8 vf = *(const bf16x8*)&lV[d][((r << 3) + ((s * 4 + quad) ^ (r & 7))) << 3];
                acc_o[dt] = __builtin_amdgcn_mfma_f32_16x16x32_bf16(pf, vf, acc_o[dt], 0, 0, 0);
            }
            __builtin_amdgcn_s_setprio(0);
        }
        __builtin_amdgcn_s_barrier();   // all reads of buf[d] done before restage
    }

    // ---- epilogue: complete the deferred cross-quad l reduction, then store ----
    float lf = lp;
    lf += __shfl_xor(lf, 16, 64);
    lf += __shfl_xor(lf, 32, 64);
    float lr[4];
#pragma unroll
    for (int r = 0; r < 4; r++) lr[r] = RCPF(__shfl(lf, quad * 4 + r, 64));
#pragma unroll
    for (int dt = 0; dt < 4; dt++) {
#pragma unroll
        for (int r = 0; r < 4; r++) {
            int row = q0 + w * 16 + quad * 4 + r;
            int col = h * HD + dt * 16 + l15;
            float v = acc_o[dt][r] * lr[r];
            O[((size_t)(b * LT + row)) * DM + col] = (bf16_t)v;
        }
    }
}

// ---------- host ----------
extern "C" void kernel_launch(void* const* d_in, const int* in_sizes, int n_in,
                              void* d_out, int out_size, void* d_ws, size_t ws_size,
                              hipStream_t stream)
{
    (void)in_sizes; (void)n_in; (void)out_size; (void)ws_size;
    const float* x    = (const float*)d_in[0];
    const float* mem  = (const float*)d_in[1];
    const float* pemb = (const float*)d_in[2];
    const float* g_sa = (const float*)d_in[4];
    const float* wq_s = (const float*)d_in[5];
    const float* wk_s = (const float*)d_in[6];
    const float* wv_s = (const float*)d_in[7];
    const float* wo_s = (const float*)d_in[8];
    const float* g_ca = (const float*)d_in[9];
    const float* wq_c = (const float*)d_in[10];
    const float* wk_c = (const float*)d_in[11];
    const float* wv_c = (const float*)d_in[12];
    const float* wo_c = (const float*)d_in[13];
    const float* g_m  = (const float*)d_in[14];
    const float* w1   = (const float*)d_in[15];
    const float* w2   = (const float*)d_in[16];
    float* out = (float*)d_out;

    const size_t OFF_KS = 4u * 1024 * 1024;
    const size_t OFF_VS = 8u * 1024 * 1024;
    const size_t OFF_KC = 12u * 1024 * 1024;
    const size_t OFF_VC = 16u * 1024 * 1024;

    char* ws = (char*)d_ws;
    const size_t MB = 1024 * 1024;
    bf16_t* wqkvTs = (bf16_t*)(ws + 0 * MB);   // [3072,1024]
    bf16_t* woTs   = (bf16_t*)(ws + 6 * MB);
    bf16_t* wqTc   = (bf16_t*)(ws + 8 * MB);
    bf16_t* wkvTc  = (bf16_t*)(ws + 10 * MB);  // [2048,1024]
    bf16_t* woTc   = (bf16_t*)(ws + 14 * MB);
    bf16_t* w1T    = (bf16_t*)(ws + 16 * MB);  // [4096,1024]
    bf16_t* w2T    = (bf16_t*)(ws + 24 * MB);  // [1024,4096]
    bf16_t* membf  = (bf16_t*)(ws + 32 * MB);  // [4096,1024]
    bf16_t* hbuf   = (bf16_t*)(ws + 40 * MB);  // [4096,1024]
    bf16_t* qbuf   = (bf16_t*)(ws + 48 * MB);  // [B,H,LT,HD]
    bf16_t* kbuf   = (bf16_t*)(ws + 56 * MB);  // [B,H,LS,HD]
    bf16_t* vbuf   = (bf16_t*)(ws + 64 * MB);  // [B,H,LS,HD]
    bf16_t* vTbuf  = (bf16_t*)(ws + 72 * MB);  // [B,H,HD,LS]
    bf16_t* Obuf   = (bf16_t*)(ws + 80 * MB);  // [B,LT,D]
    float*  attn_x  = (float*)(ws + 88 * MB);  // fp32 [4096,1024]
    float*  cross_x = (float*)(ws + 112 * MB); // fp32 [4096,1024]
    // FFN-phase overlays (attention buffers dead by then):
    bf16_t* ffnmid  = (bf16_t*)(ws + 48 * MB); // [4096,4096] bf16, 48..80
    float*  part    = (float*)(ws + 80 * MB);  // 2x fp32 [4096,1024], 80..112

    dim3 tb(32, 8);
    TPtrs tp;
    tp.in[0] = wq_s; tp.out[0] = wqkvTs;
    tp.in[1] = wk_s; tp.out[1] = wqkvTs + 1024 * 1024;
    tp.in[2] = wv_s; tp.out[2] = wqkvTs + 2 * 1024 * 1024;
    tp.in[3] = wo_s; tp.out[3] = woTs;
    tp.in[4] = wq_c; tp.out[4] = wqTc;
    tp.in[5] = wk_c; tp.out[5] = wkvTc;
    tp.in[6] = wv_c; tp.out[6] = wkvTc + 1024 * 1024;
    tp.in[7] = wo_c; tp.out[7] = woTc;
    transpose8_f2bf<<<dim3(32, 32, 8), tb, 0, stream>>>(tp);
    transpose_f2bf<<<dim3(128, 32), tb, 0, stream>>>(w1, w1T, DM, FF);
    transpose_f2bf<<<dim3(32, 128), tb, 0, stream>>>(w2, w2T, FF, DM);

    f2bf_kernel<<<4096, 256, 0, stream>>>(mem, membf, (size_t)BB * LS * DM);

    // ---- self-attention block ----
    rmsnorm_kernel<<<BB * LT, 256, 0, stream>>>(x, g_sa, hbuf);
    gemm_qkv<<<dim3(32, 24), 256, 0, stream>>>(
        hbuf, wqkvTs, 24, hbuf, wqkvTs, 0,
        qbuf, out + OFF_KS, kbuf, out + OFF_VS, vbuf);
    transpose_bf<<<dim3(32, 2, 64), tb, 0, stream>>>(vbuf, vTbuf);
    flash_attn<true><<<dim3(16, 64), 256, 0, stream>>>(qbuf, kbuf, vTbuf, nullptr, Obuf);
    gemm_bt<EP_RES, 1><<<dim3(32, 8), 256, 0, stream>>>(
        Obuf, woTs, 1024, 1024, attn_x, x, nullptr);

    // ---- cross-attention block ----
    rmsnorm_kernel<<<BB * LT, 256, 0, stream>>>(attn_x, g_ca, hbuf);
    gemm_qkv<<<dim3(32, 24), 256, 0, stream>>>(
        hbuf, wqTc, 8, membf, wkvTc, 1,
        qbuf, out + OFF_KC, kbuf, out + OFF_VC, vbuf);
    transpose_bf<<<dim3(32, 2, 64), tb, 0, stream>>>(vbuf, vTbuf);
    flash_attn<false><<<dim3(16, 64), 256, 0, stream>>>(qbuf, kbuf, vTbuf, pemb, Obuf);
    gemm_bt<EP_RES, 1><<<dim3(32, 8), 256, 0, stream>>>(
        Obuf, woTc, 1024, 1024, cross_x, attn_x, nullptr);

    // ---- FFN block ----
    rmsnorm_kernel<<<BB * LT, 256, 0, stream>>>(cross_x, g_m, hbuf);
    gemm_bt<EP_RELU, 1><<<dim3(32, 32), 256, 0, stream>>>(
        hbuf, w1T, 4096, 1024, nullptr, nullptr, ffnmid);
    gemm_bt<EP_PART, 2><<<dim3(32, 8, 2), 256, 0, stream>>>(
        ffnmid, w2T, 1024, 4096, part, nullptr, nullptr);
    reduce2_res<<<4096, 256, 0, stream>>>(part, cross_x, out);
}